// Round 1
// baseline (1416.240 us; speedup 1.0000x reference)
//
#include <hip/hip_runtime.h>

#define NUM_NODES 100000
#define OUT_CH 32
#define NUM_EDGES 3200000

// Kernel 1: out[i] = b[i % 32] (vectorized as float4), and init ws_min = INT_MAX.
__global__ void init_out_kernel(const float* __restrict__ b, float* __restrict__ out,
                                int* __restrict__ ws_min) {
    int i = blockIdx.x * blockDim.x + threadIdx.x;  // [0, 800000) float4 index
    float4 bb = ((const float4*)b)[i & 7];          // row = 8 float4 groups
    ((float4*)out)[i] = bb;
    if (i == 0) *ws_min = 0x7fffffff;
}

// Kernel 2: min over row[] -> ws_min
__global__ void min_kernel(const int* __restrict__ row, int n, int* __restrict__ ws_min) {
    int tid = blockIdx.x * blockDim.x + threadIdx.x;
    int stride = gridDim.x * blockDim.x;
    int m = 0x7fffffff;
    for (int i = tid; i < n; i += stride) m = min(m, row[i]);
    #pragma unroll
    for (int off = 32; off > 0; off >>= 1) m = min(m, __shfl_down(m, off, 64));
    if ((threadIdx.x & 63) == 0) atomicMin(ws_min, m);
}

// Kernel 3: transpose W [32, NUM_NODES] -> Wt [NUM_NODES, 32]
__global__ void transpose_kernel(const float* __restrict__ W, float* __restrict__ Wt) {
    __shared__ float tile[32][33];
    int tx = threadIdx.x;   // 0..31
    int c  = threadIdx.y;   // channel 0..31
    int colBase = blockIdx.x * 32;
    // coalesced read: lanes sweep consecutive columns of channel c
    tile[c][tx] = W[c * NUM_NODES + colBase + tx];
    __syncthreads();
    // coalesced write: lanes sweep consecutive channels of column colBase+c
    Wt[(colBase + c) * 32 + tx] = tile[tx][c];
}

// Kernel 4: scatter-add. 8 threads per edge, float4 gather from Wt, 4 atomicAdds.
__global__ void scatter_kernel(const int* __restrict__ edge, const float* __restrict__ Wt,
                               const int* __restrict__ ws_min, float* __restrict__ out) {
    int gid = blockIdx.x * blockDim.x + threadIdx.x;  // < 25.6M, fits int
    int e   = gid >> 3;
    int sub = gid & 7;
    int rmin = *ws_min;
    int r = edge[e] - rmin;              // row
    int c = edge[NUM_EDGES + e];         // col
    float4 w = ((const float4*)Wt)[c * 8 + sub];
    float* o = out + (size_t)r * 32 + sub * 4;
    atomicAdd(o + 0, w.x);
    atomicAdd(o + 1, w.y);
    atomicAdd(o + 2, w.z);
    atomicAdd(o + 3, w.w);
}

extern "C" void kernel_launch(void* const* d_in, const int* in_sizes, int n_in,
                              void* d_out, int out_size, void* d_ws, size_t ws_size,
                              hipStream_t stream) {
    const int*   edge = (const int*)d_in[0];     // [2, NUM_EDGES] int32
    const float* W    = (const float*)d_in[1];   // [32, NUM_NODES]
    const float* b    = (const float*)d_in[2];   // [32]
    float* out = (float*)d_out;                  // [NUM_NODES, 32]

    int*   ws_min = (int*)d_ws;
    float* Wt     = (float*)((char*)d_ws + 256); // 12.8 MB transposed W

    // out init (3.2M floats = 800000 float4) + ws_min init
    init_out_kernel<<<800000 / 256, 256, 0, stream>>>(b, out, ws_min);
    // row min
    min_kernel<<<1024, 256, 0, stream>>>(edge, NUM_EDGES, ws_min);
    // W transpose (100000 / 32 = 3125 tiles)
    transpose_kernel<<<3125, dim3(32, 32), 0, stream>>>(W, Wt);
    // scatter: 3.2M edges * 8 threads = 25.6M threads
    scatter_kernel<<<(NUM_EDGES * 8) / 256, 256, 0, stream>>>(edge, Wt, ws_min, out);
}

// Round 2
// 569.090 us; speedup vs baseline: 2.4886x; 2.4886x over previous
//
#include <hip/hip_runtime.h>

#define NUM_NODES 100000
#define OUT_CH 32
#define NUM_EDGES 3200000

#define SCAN_BLOCK 256
#define SCAN_ITEMS 4
#define SCAN_TILE  1024   // SCAN_BLOCK * SCAN_ITEMS
#define NBLOCKS_SCAN 98   // ceil(100000 / 1024)

// ---------------- init: zero counts, set ws_min = INT_MAX ----------------
__global__ void init_kernel(int* __restrict__ counts, int* __restrict__ ws_min) {
    int i = blockIdx.x * blockDim.x + threadIdx.x;
    if (i < NUM_NODES) counts[i] = 0;
    if (i == 0) *ws_min = 0x7fffffff;
}

// ---------------- row min ----------------
__global__ void min_kernel(const int* __restrict__ row, int* __restrict__ ws_min) {
    int tid = blockIdx.x * blockDim.x + threadIdx.x;
    int stride = gridDim.x * blockDim.x;
    int m = 0x7fffffff;
    for (int i = tid; i < NUM_EDGES; i += stride) m = min(m, row[i]);
    #pragma unroll
    for (int off = 32; off > 0; off >>= 1) m = min(m, __shfl_down(m, off, 64));
    if ((threadIdx.x & 63) == 0) atomicMin(ws_min, m);
}

// ---------------- transpose W [32, N] -> Wt [N, 32] ----------------
__global__ void transpose_kernel(const float* __restrict__ W, float* __restrict__ Wt) {
    __shared__ float tile[32][33];
    int tx = threadIdx.x;   // 0..31
    int c  = threadIdx.y;   // 0..31
    int colBase = blockIdx.x * 32;
    tile[c][tx] = W[c * NUM_NODES + colBase + tx];
    __syncthreads();
    Wt[(colBase + c) * 32 + tx] = tile[tx][c];
}

// ---------------- histogram of rows ----------------
__global__ void hist_kernel(const int* __restrict__ edge, const int* __restrict__ ws_min,
                            int* __restrict__ counts) {
    int e = blockIdx.x * blockDim.x + threadIdx.x;
    int rmin = *ws_min;
    int r = edge[e] - rmin;
    atomicAdd(&counts[r], 1);
}

// ---------------- scan step 1: per-tile reduce ----------------
__global__ void scan_reduce(const int* __restrict__ counts, int* __restrict__ blocksums) {
    int t = threadIdx.x;
    int base = blockIdx.x * SCAN_TILE + t * SCAN_ITEMS;
    int s = 0;
    #pragma unroll
    for (int k = 0; k < SCAN_ITEMS; k++) {
        int i = base + k;
        if (i < NUM_NODES) s += counts[i];
    }
    #pragma unroll
    for (int off = 32; off > 0; off >>= 1) s += __shfl_down(s, off, 64);
    __shared__ int ws[4];
    if ((t & 63) == 0) ws[t >> 6] = s;
    __syncthreads();
    if (t == 0) blocksums[blockIdx.x] = ws[0] + ws[1] + ws[2] + ws[3];
}

// ---------------- scan step 2: exclusive scan of block sums (single block) ----------------
__global__ void scan_blocksums(int* __restrict__ blocksums) {
    __shared__ int tmp[128];
    int t = threadIdx.x;
    int v = (t < NBLOCKS_SCAN) ? blocksums[t] : 0;
    tmp[t] = v;
    __syncthreads();
    int acc = v;
    for (int off = 1; off < 128; off <<= 1) {
        int u = (t >= off) ? tmp[t - off] : 0;
        __syncthreads();
        acc += u;
        tmp[t] = acc;
        __syncthreads();
    }
    if (t < NBLOCKS_SCAN) blocksums[t] = acc - v;   // exclusive
}

// ---------------- scan step 3: write exclusive prefix into cursor ----------------
__global__ void scan_write(const int* __restrict__ counts, const int* __restrict__ blocksums,
                           int* __restrict__ cursor) {
    int t = threadIdx.x;
    int base = blockIdx.x * SCAN_TILE + t * SCAN_ITEMS;
    int v[SCAN_ITEMS];
    int s = 0;
    #pragma unroll
    for (int k = 0; k < SCAN_ITEMS; k++) {
        int i = base + k;
        v[k] = (i < NUM_NODES) ? counts[i] : 0;
        s += v[k];
    }
    __shared__ int tmp[SCAN_BLOCK];
    tmp[t] = s;
    __syncthreads();
    int acc = s;
    for (int off = 1; off < SCAN_BLOCK; off <<= 1) {
        int u = (t >= off) ? tmp[t - off] : 0;
        __syncthreads();
        acc += u;
        tmp[t] = acc;
        __syncthreads();
    }
    int run = acc - s + blocksums[blockIdx.x];  // exclusive offset for this thread's first item
    #pragma unroll
    for (int k = 0; k < SCAN_ITEMS; k++) {
        int i = base + k;
        if (i < NUM_NODES) cursor[i] = run;
        run += v[k];
    }
}

// ---------------- scatter cols into row-grouped order ----------------
// cursor starts as exclusive prefix (row starts); after this kernel cursor[r] == row end.
__global__ void scatter_cols(const int* __restrict__ edge, const int* __restrict__ ws_min,
                             int* __restrict__ cursor, int* __restrict__ sorted_col) {
    int e = blockIdx.x * blockDim.x + threadIdx.x;
    int rmin = *ws_min;
    int r = edge[e] - rmin;
    int c = edge[NUM_EDGES + e];
    int pos = atomicAdd(&cursor[r], 1);
    sorted_col[pos] = c;
}

// ---------------- gather-sum: 8 lanes per row, float4, bias folded ----------------
__global__ void gather_kernel(const int* __restrict__ sorted_col, const int* __restrict__ cursor,
                              const float* __restrict__ Wt, const float* __restrict__ b,
                              float* __restrict__ out) {
    int t = blockIdx.x * blockDim.x + threadIdx.x;   // [0, 800000)
    int r   = t >> 3;
    int sub = t & 7;
    int start = (r == 0) ? 0 : cursor[r - 1];
    int end   = cursor[r];
    float4 acc = ((const float4*)b)[sub];
    const float4* Wt4 = (const float4*)Wt;
    for (int i = start; i < end; i++) {
        int c = sorted_col[i];
        float4 w = Wt4[c * 8 + sub];
        acc.x += w.x; acc.y += w.y; acc.z += w.z; acc.w += w.w;
    }
    ((float4*)out)[(size_t)r * 8 + sub] = acc;
}

extern "C" void kernel_launch(void* const* d_in, const int* in_sizes, int n_in,
                              void* d_out, int out_size, void* d_ws, size_t ws_size,
                              hipStream_t stream) {
    const int*   edge = (const int*)d_in[0];     // [2, NUM_EDGES]
    const float* W    = (const float*)d_in[1];   // [32, NUM_NODES]
    const float* b    = (const float*)d_in[2];   // [32]
    float* out = (float*)d_out;                  // [NUM_NODES, 32]

    // workspace layout
    char* ws = (char*)d_ws;
    int*   ws_min     = (int*)ws;                        // 4 B
    int*   counts     = (int*)(ws + 256);                // 400 KB
    int*   cursor     = (int*)(ws + 256 + 400000 + 128); // 400 KB
    int*   blocksums  = (int*)(ws + 256 + 800000 + 256); // ~400 B
    float* Wt         = (float*)(ws + (1u << 20));       // 12.8 MB at 1 MiB
    int*   sorted_col = (int*)(ws + (16u << 20));        // 12.8 MB at 16 MiB

    init_kernel<<<(NUM_NODES + 255) / 256, 256, 0, stream>>>(counts, ws_min);
    min_kernel<<<512, 256, 0, stream>>>(edge, ws_min);
    transpose_kernel<<<NUM_NODES / 32, dim3(32, 32), 0, stream>>>(W, Wt);
    hist_kernel<<<NUM_EDGES / 256, 256, 0, stream>>>(edge, ws_min, counts);
    scan_reduce<<<NBLOCKS_SCAN, SCAN_BLOCK, 0, stream>>>(counts, blocksums);
    scan_blocksums<<<1, 128, 0, stream>>>(blocksums);
    scan_write<<<NBLOCKS_SCAN, SCAN_BLOCK, 0, stream>>>(counts, blocksums, cursor);
    scatter_cols<<<NUM_EDGES / 256, 256, 0, stream>>>(edge, ws_min, cursor, sorted_col);
    gather_kernel<<<(NUM_NODES * 8) / 256, 256, 0, stream>>>(sorted_col, cursor, Wt, b, out);
}